// Round 2
// baseline (266.827 us; speedup 1.0000x reference)
//
#include <hip/hip_runtime.h>
#include <math.h>

#define NB1   4096
#define NBTOT 8192
#define NFD   128
#define QCOLS 2048
#define RT    64
#define CT    64

// ---------------------------------------------------------------------------
// Kernel 1: row L2-normalize. One block (128 threads) per row.
// ---------------------------------------------------------------------------
__global__ void norm_k(const float* __restrict__ f1, const float* __restrict__ f2,
                       float* __restrict__ nf) {
    const int row = blockIdx.x;
    const int k = threadIdx.x;  // 0..127
    const float* src = (row < NB1) ? (f1 + (size_t)row * NFD)
                                   : (f2 + (size_t)(row - NB1) * NFD);
    float x = src[k];
    float s = x * x;
#pragma unroll
    for (int m = 32; m >= 1; m >>= 1) s += __shfl_xor(s, m, 64);
    __shared__ float part[2];
    if ((k & 63) == 0) part[k >> 6] = s;
    __syncthreads();
    const float tot = part[0] + part[1];
    const float inv = 1.0f / fmaxf(sqrtf(tot), 1e-12f);
    nf[(size_t)row * NFD + k] = x * inv;
}

// ---------------------------------------------------------------------------
// Kernel 2: fused sim-tile + row stats.
// blockIdx.x = q (column quarter, 0..3; q<2 -> class0 cols, q>=2 -> class1)
// blockIdx.y = row tile (64 rows each, 0..127)
// Block computes 64 x 2048 dot products (K=128) and reduces per row:
//   same-class block -> running max (excluding diagonal)  -> posp[q&1][row]
//   diff-class block -> running sum of exp(sim)           -> sexpp[q&1][row]
// LDS tiles are k-major: As[k*64 + r]. Reads: float4 along rows (<=2-way
// conflicts). Transpose-writes: bank = row%32 across the wave -> 2-way (free).
// ---------------------------------------------------------------------------
__global__ __launch_bounds__(256, 2) void simstat_k(const float* __restrict__ nf,
                                                    float* __restrict__ posp,
                                                    float* __restrict__ sexpp) {
    __shared__ float As[NFD * RT];  // 32 KB
    __shared__ float Bs[NFD * CT];  // 32 KB

    const int q    = blockIdx.x;
    const int rt   = blockIdx.y;
    const int row0 = rt * RT;
    const int col0q = q * QCOLS;
    const int rcls = (row0 >= NB1);
    const int ccls = (q >= 2);
    const bool same = (rcls == ccls);
    const int p = q & 1;

    const int t  = threadIdx.x;
    const int tx = t & 15;   // 16 col-groups of 4
    const int ty = t >> 4;   // 16 row-groups of 4

    // ---- stage A tile (64 rows x 128 k), k-major, once ----
    {
        const int r  = t & 63;
        const int ks = (t >> 6) * 32;
        const float* src = nf + (size_t)(row0 + r) * NFD + ks;
#pragma unroll
        for (int i = 0; i < 8; ++i) {
            const float4 v = *reinterpret_cast<const float4*>(src + i * 4);
            const int k = ks + i * 4;
            As[(k + 0) * RT + r] = v.x;
            As[(k + 1) * RT + r] = v.y;
            As[(k + 2) * RT + r] = v.z;
            As[(k + 3) * RT + r] = v.w;
        }
    }

    float stat[4];
#pragma unroll
    for (int r = 0; r < 4; ++r) stat[r] = same ? -3.0e38f : 0.0f;
    const float invtau = 1.0f / 0.07f;

    for (int ct = 0; ct < QCOLS / CT; ++ct) {
        const int c0 = col0q + ct * CT;
        __syncthreads();  // previous iteration done reading Bs
        {
            const int r  = t & 63;
            const int ks = (t >> 6) * 32;
            const float* src = nf + (size_t)(c0 + r) * NFD + ks;
#pragma unroll
            for (int i = 0; i < 8; ++i) {
                const float4 v = *reinterpret_cast<const float4*>(src + i * 4);
                const int k = ks + i * 4;
                Bs[(k + 0) * CT + r] = v.x;
                Bs[(k + 1) * CT + r] = v.y;
                Bs[(k + 2) * CT + r] = v.z;
                Bs[(k + 3) * CT + r] = v.w;
            }
        }
        __syncthreads();

        float acc[4][4];
#pragma unroll
        for (int r = 0; r < 4; ++r)
#pragma unroll
            for (int c = 0; c < 4; ++c) acc[r][c] = 0.0f;

#pragma unroll 8
        for (int k = 0; k < NFD; ++k) {
            const float4 a = *reinterpret_cast<const float4*>(&As[k * RT + 4 * ty]);
            const float4 b = *reinterpret_cast<const float4*>(&Bs[k * CT + 4 * tx]);
            acc[0][0] += a.x * b.x; acc[0][1] += a.x * b.y; acc[0][2] += a.x * b.z; acc[0][3] += a.x * b.w;
            acc[1][0] += a.y * b.x; acc[1][1] += a.y * b.y; acc[1][2] += a.y * b.z; acc[1][3] += a.y * b.w;
            acc[2][0] += a.z * b.x; acc[2][1] += a.z * b.y; acc[2][2] += a.z * b.z; acc[2][3] += a.z * b.w;
            acc[3][0] += a.w * b.x; acc[3][1] += a.w * b.y; acc[3][2] += a.w * b.z; acc[3][3] += a.w * b.w;
        }

        if (same) {
#pragma unroll
            for (int r = 0; r < 4; ++r) {
                const int grow = row0 + 4 * ty + r;
#pragma unroll
                for (int c = 0; c < 4; ++c) {
                    const int gcol = c0 + 4 * tx + c;
                    const float sim = acc[r][c] * invtau;
                    if (gcol != grow) stat[r] = fmaxf(stat[r], sim);
                }
            }
        } else {
#pragma unroll
            for (int r = 0; r < 4; ++r)
#pragma unroll
                for (int c = 0; c < 4; ++c)
                    stat[r] += __expf(acc[r][c] * invtau);
        }
    }

    // reduce across tx (lanes xor bits 0..3), then lane tx==0 writes its 4 rows
#pragma unroll
    for (int m = 1; m <= 8; m <<= 1) {
#pragma unroll
        for (int r = 0; r < 4; ++r) {
            const float o = __shfl_xor(stat[r], m, 64);
            stat[r] = same ? fmaxf(stat[r], o) : (stat[r] + o);
        }
    }
    if (tx == 0) {
        float* dst = (same ? posp : sexpp) + (size_t)p * NBTOT;
#pragma unroll
        for (int r = 0; r < 4; ++r) dst[row0 + 4 * ty + r] = stat[r];
    }
}

// ---------------------------------------------------------------------------
// Kernel 3: combine quarter-partials, per-row loss, mean. One block.
// loss_i = log(exp(pos)+S) - pos = log1p(S * exp(-pos))
// ---------------------------------------------------------------------------
__global__ void loss_k(const float* __restrict__ posp, const float* __restrict__ sexpp,
                       float* __restrict__ out) {
    const int t = threadIdx.x;  // 256
    float s = 0.0f;
    for (int i = t; i < NBTOT; i += 256) {
        const float pv = fmaxf(posp[i], posp[NBTOT + i]);
        const float se = sexpp[i] + sexpp[NBTOT + i];
        s += log1pf(se * __expf(-pv));
    }
#pragma unroll
    for (int m = 32; m >= 1; m >>= 1) s += __shfl_xor(s, m, 64);
    __shared__ float part[4];
    if ((t & 63) == 0) part[t >> 6] = s;
    __syncthreads();
    if (t == 0) out[0] = (part[0] + part[1] + part[2] + part[3]) / (float)NBTOT;
}

// ---------------------------------------------------------------------------
extern "C" void kernel_launch(void* const* d_in, const int* in_sizes, int n_in,
                              void* d_out, int out_size, void* d_ws, size_t ws_size,
                              hipStream_t stream) {
    const float* f1 = (const float*)d_in[0];
    const float* f2 = (const float*)d_in[1];

    float* nf    = (float*)d_ws;                    // 8192*128 f32 = 4 MB
    float* posp  = nf + (size_t)NBTOT * NFD;        // 2*8192 f32
    float* sexpp = posp + 2 * NBTOT;                // 2*8192 f32

    norm_k<<<NBTOT, NFD, 0, stream>>>(f1, f2, nf);
    simstat_k<<<dim3(4, 128), 256, 0, stream>>>(nf, posp, sexpp);
    loss_k<<<1, 256, 0, stream>>>(posp, sexpp, (float*)d_out);
}

// Round 3
// 124.809 us; speedup vs baseline: 2.1379x; 2.1379x over previous
//
#include <hip/hip_runtime.h>
#include <math.h>

#define NB1   4096
#define NBTOT 8192
#define NFD   128
#define QCOLS 2048
#define BROWS 128
#define BCOLS 128
#define NTILES (QCOLS / BCOLS)   // 16

typedef __attribute__((ext_vector_type(8))) short bf16x8;
typedef __attribute__((ext_vector_type(4))) float f32x4;
typedef unsigned short u16;

__device__ __forceinline__ u16 f2bf(float x) {
    unsigned u = __builtin_bit_cast(unsigned, x);
    unsigned r = u + 0x7fffu + ((u >> 16) & 1u);   // RNE, inputs are finite/normal
    return (u16)(r >> 16);
}
__device__ __forceinline__ float bf2f(u16 h) {
    return __builtin_bit_cast(float, ((unsigned)h) << 16);
}

// ---------------------------------------------------------------------------
// Kernel 1: row L2-normalize, emit bf16 hi/lo split (x = hi + lo exactly to
// ~2^-18 relative). One block (128 threads) per row.
// ---------------------------------------------------------------------------
__global__ void norm_k(const float* __restrict__ f1, const float* __restrict__ f2,
                       u16* __restrict__ nfh, u16* __restrict__ nfl) {
    const int row = blockIdx.x;
    const int k = threadIdx.x;  // 0..127
    const float* src = (row < NB1) ? (f1 + (size_t)row * NFD)
                                   : (f2 + (size_t)(row - NB1) * NFD);
    float x = src[k];
    float s = x * x;
#pragma unroll
    for (int m = 32; m >= 1; m >>= 1) s += __shfl_xor(s, m, 64);
    __shared__ float part[2];
    if ((k & 63) == 0) part[k >> 6] = s;
    __syncthreads();
    const float inv = 1.0f / fmaxf(sqrtf(part[0] + part[1]), 1e-12f);
    const float xn = x * inv;
    const u16 h = f2bf(xn);
    const u16 l = f2bf(xn - bf2f(h));
    nfh[(size_t)row * NFD + k] = h;
    nfl[(size_t)row * NFD + k] = l;
}

// ---------------------------------------------------------------------------
// Kernel 2: MFMA sim-stats. Grid (4 quarters, 64 row-tiles) = 256 blocks,
// 512 threads = 8 waves (2 row-stripes x 4 col-stripes), tile 128x128, K=128
// fully LDS-resident. sim = Ah*Bh + Ah*Bl + Al*Bh accumulated into one acc.
// LDS per array [128 rows][128 k] bf16 with XOR swizzle kbyte^((row&7)<<4).
// B staged reg->LDS with issue-early/write-late prefetch (T14).
// ---------------------------------------------------------------------------
__global__ __launch_bounds__(512, 2) void simstat_mfma(const u16* __restrict__ nfh,
                                                       const u16* __restrict__ nfl,
                                                       float* __restrict__ posp,
                                                       float* __restrict__ sexpp) {
    extern __shared__ __align__(16) char smem[];
    const int AH = 0, AL = 32768, BH = 65536, BL = 98304;

    const int q    = blockIdx.x;
    const int rt   = blockIdx.y;
    const int row0 = rt * BROWS;
    const int col0q = q * QCOLS;
    const bool same = ((row0 >= NB1) == (q >= 2));
    const int p = q & 1;

    const int t    = threadIdx.x;
    const int w    = t >> 6;
    const int lane = t & 63;
    const int lr   = lane & 15;   // frag row/col within 16
    const int lg   = lane >> 4;   // k-group / C row-group
    const int rowbase = 64 * (w & 1);
    const int colbase = 32 * (w >> 1);

    // staging map: thread -> (row 0..127, k-chunk 0..3 of 32 elems)
    const int sr   = t >> 2;
    const int sgo  = (t & 3) * 32;

    uint4 pbh[4], pbl[4];
    // ---- prologue: stage A (once) and B tile 0 ----
    {
        uint4 pah[4], pal[4];
        const uint4* gh = (const uint4*)(nfh + (size_t)(row0 + sr) * NFD + sgo);
        const uint4* gl = (const uint4*)(nfl + (size_t)(row0 + sr) * NFD + sgo);
#pragma unroll
        for (int j = 0; j < 4; ++j) { pah[j] = gh[j]; pal[j] = gl[j]; }
        const uint4* gh2 = (const uint4*)(nfh + (size_t)(col0q + sr) * NFD + sgo);
        const uint4* gl2 = (const uint4*)(nfl + (size_t)(col0q + sr) * NFD + sgo);
#pragma unroll
        for (int j = 0; j < 4; ++j) { pbh[j] = gh2[j]; pbl[j] = gl2[j]; }
#pragma unroll
        for (int j = 0; j < 4; ++j) {
            const int kb  = (sgo + 8 * j) * 2;
            const int off = sr * 256 + (kb ^ ((sr & 7) << 4));
            *(uint4*)(smem + AH + off) = pah[j];
            *(uint4*)(smem + AL + off) = pal[j];
            *(uint4*)(smem + BH + off) = pbh[j];
            *(uint4*)(smem + BL + off) = pbl[j];
        }
    }
    __syncthreads();

    float stat[4][4];
#pragma unroll
    for (int fa = 0; fa < 4; ++fa)
#pragma unroll
        for (int r = 0; r < 4; ++r) stat[fa][r] = same ? -3.0e38f : 0.0f;
    const float invtau = 1.0f / 0.07f;

    for (int tile = 0; tile < NTILES; ++tile) {
        const int col0 = col0q + tile * BCOLS;
        // issue next B-tile loads early (complete during compute)
        if (tile + 1 < NTILES) {
            const uint4* gh = (const uint4*)(nfh + (size_t)(col0 + BCOLS + sr) * NFD + sgo);
            const uint4* gl = (const uint4*)(nfl + (size_t)(col0 + BCOLS + sr) * NFD + sgo);
#pragma unroll
            for (int j = 0; j < 4; ++j) { pbh[j] = gh[j]; pbl[j] = gl[j]; }
        }

        f32x4 acc[4][2];
#pragma unroll
        for (int fa = 0; fa < 4; ++fa)
#pragma unroll
            for (int fb = 0; fb < 2; ++fb) {
                f32x4 z = {0.0f, 0.0f, 0.0f, 0.0f};
                acc[fa][fb] = z;
            }

#pragma unroll
        for (int ks = 0; ks < 4; ++ks) {
            const int kb = 64 * ks + 16 * lg;
            bf16x8 ah[4], al[4], bh[2], bl[2];
#pragma unroll
            for (int fa = 0; fa < 4; ++fa) {
                const int row = rowbase + 16 * fa + lr;
                const int off = row * 256 + (kb ^ ((row & 7) << 4));
                ah[fa] = *(const bf16x8*)(smem + AH + off);
                al[fa] = *(const bf16x8*)(smem + AL + off);
            }
#pragma unroll
            for (int fb = 0; fb < 2; ++fb) {
                const int row = colbase + 16 * fb + lr;
                const int off = row * 256 + (kb ^ ((row & 7) << 4));
                bh[fb] = *(const bf16x8*)(smem + BH + off);
                bl[fb] = *(const bf16x8*)(smem + BL + off);
            }
#pragma unroll
            for (int fa = 0; fa < 4; ++fa)
#pragma unroll
                for (int fb = 0; fb < 2; ++fb) {
                    acc[fa][fb] = __builtin_amdgcn_mfma_f32_16x16x32_bf16(ah[fa], bh[fb], acc[fa][fb], 0, 0, 0);
                    acc[fa][fb] = __builtin_amdgcn_mfma_f32_16x16x32_bf16(ah[fa], bl[fb], acc[fa][fb], 0, 0, 0);
                    acc[fa][fb] = __builtin_amdgcn_mfma_f32_16x16x32_bf16(al[fa], bh[fb], acc[fa][fb], 0, 0, 0);
                }
        }

        // epilogue: C/D layout col=lane&15, row=(lane>>4)*4+reg (m89-verified)
        if (same) {
#pragma unroll
            for (int fa = 0; fa < 4; ++fa)
#pragma unroll
                for (int fb = 0; fb < 2; ++fb)
#pragma unroll
                    for (int r = 0; r < 4; ++r) {
                        const int rl = rowbase + 16 * fa + 4 * lg + r;
                        const int cl = colbase + 16 * fb + lr;
                        const float sim = acc[fa][fb][r] * invtau;
                        const bool dg = (row0 + rl) == (col0 + cl);
                        stat[fa][r] = dg ? stat[fa][r] : fmaxf(stat[fa][r], sim);
                    }
        } else {
#pragma unroll
            for (int fa = 0; fa < 4; ++fa)
#pragma unroll
                for (int fb = 0; fb < 2; ++fb)
#pragma unroll
                    for (int r = 0; r < 4; ++r)
                        stat[fa][r] += __expf(acc[fa][fb][r] * invtau);
        }

        __syncthreads();  // all waves done reading B tile
        if (tile + 1 < NTILES) {
#pragma unroll
            for (int j = 0; j < 4; ++j) {
                const int kb  = (sgo + 8 * j) * 2;
                const int off = sr * 256 + (kb ^ ((sr & 7) << 4));
                *(uint4*)(smem + BH + off) = pbh[j];
                *(uint4*)(smem + BL + off) = pbl[j];
            }
            __syncthreads();
        }
    }

    // reduce across the 16 cols held by lanes lr=0..15 (same lg)
#pragma unroll
    for (int m = 1; m <= 8; m <<= 1) {
#pragma unroll
        for (int fa = 0; fa < 4; ++fa)
#pragma unroll
            for (int r = 0; r < 4; ++r) {
                const float o = __shfl_xor(stat[fa][r], m, 64);
                stat[fa][r] = same ? fmaxf(stat[fa][r], o) : (stat[fa][r] + o);
            }
    }

    // cross-wave combine: scratch[stripe][colwave][64 rows] (reuses AH region)
    float* scratch = (float*)smem;
    if (lr == 0) {
#pragma unroll
        for (int fa = 0; fa < 4; ++fa)
#pragma unroll
            for (int r = 0; r < 4; ++r)
                scratch[(w & 1) * 256 + (w >> 1) * 64 + 16 * fa + 4 * lg + r] = stat[fa][r];
    }
    __syncthreads();
    if (t < 128) {
        const int st = t >> 6, rr = t & 63;
        const float v0 = scratch[st * 256 + 0 * 64 + rr];
        const float v1 = scratch[st * 256 + 1 * 64 + rr];
        const float v2 = scratch[st * 256 + 2 * 64 + rr];
        const float v3 = scratch[st * 256 + 3 * 64 + rr];
        const float v = same ? fmaxf(fmaxf(v0, v1), fmaxf(v2, v3)) : (v0 + v1 + v2 + v3);
        (same ? posp : sexpp)[(size_t)p * NBTOT + row0 + t] = v;
    }
}

// ---------------------------------------------------------------------------
// Kernel 3: combine quarter-partials, per-row loss, mean. One block.
// ---------------------------------------------------------------------------
__global__ void loss_k(const float* __restrict__ posp, const float* __restrict__ sexpp,
                       float* __restrict__ out) {
    const int t = threadIdx.x;  // 256
    float s = 0.0f;
    for (int i = t; i < NBTOT; i += 256) {
        const float pv = fmaxf(posp[i], posp[NBTOT + i]);
        const float se = sexpp[i] + sexpp[NBTOT + i];
        s += log1pf(se * __expf(-pv));
    }
#pragma unroll
    for (int m = 32; m >= 1; m >>= 1) s += __shfl_xor(s, m, 64);
    __shared__ float part[4];
    if ((t & 63) == 0) part[t >> 6] = s;
    __syncthreads();
    if (t == 0) out[0] = (part[0] + part[1] + part[2] + part[3]) / (float)NBTOT;
}

// ---------------------------------------------------------------------------
extern "C" void kernel_launch(void* const* d_in, const int* in_sizes, int n_in,
                              void* d_out, int out_size, void* d_ws, size_t ws_size,
                              hipStream_t stream) {
    const float* f1 = (const float*)d_in[0];
    const float* f2 = (const float*)d_in[1];

    u16*   nfh   = (u16*)d_ws;                       // 8192*128 bf16 = 2 MB
    u16*   nfl   = nfh + (size_t)NBTOT * NFD;        // 2 MB
    float* posp  = (float*)(nfl + (size_t)NBTOT * NFD);
    float* sexpp = posp + 2 * NBTOT;

    (void)hipFuncSetAttribute(reinterpret_cast<const void*>(simstat_mfma),
                              hipFuncAttributeMaxDynamicSharedMemorySize, 131072);

    norm_k<<<NBTOT, NFD, 0, stream>>>(f1, f2, nfh, nfl);
    simstat_mfma<<<dim3(4, 64), 512, 131072, stream>>>(nfh, nfl, posp, sexpp);
    loss_k<<<1, 256, 0, stream>>>(posp, sexpp, (float*)d_out);
}

// Round 4
// 73.021 us; speedup vs baseline: 3.6541x; 1.7092x over previous
//
#include <hip/hip_runtime.h>
#include <math.h>
#include <stdint.h>

#define NB1   4096
#define NBTOT 8192
#define NFD   128
#define QCOLS 2048
#define BROWS 128
#define BCOLS 128
#define NTILES (QCOLS / BCOLS)   // 16

typedef __attribute__((ext_vector_type(8))) short bf16x8;
typedef __attribute__((ext_vector_type(4))) float f32x4;
typedef unsigned short u16;

__device__ __forceinline__ u16 f2bf(float x) {
    unsigned u = __builtin_bit_cast(unsigned, x);
    unsigned r = u + 0x7fffu + ((u >> 16) & 1u);   // RNE (inputs finite/normal)
    return (u16)(r >> 16);
}
__device__ __forceinline__ float bf2f(u16 h) {
    return __builtin_bit_cast(float, ((unsigned)h) << 16);
}

// async 16B global->LDS; lds base is wave-uniform, HW adds lane*16
__device__ __forceinline__ void gl16(const u16* g, char* l) {
    __builtin_amdgcn_global_load_lds(
        (const __attribute__((address_space(1))) unsigned int*)g,
        (__attribute__((address_space(3))) unsigned int*)l,
        16, 0, 0);
}

// ---------------------------------------------------------------------------
// Kernel 1: row L2-normalize -> bf16 hi/lo split. One wave per row.
// ---------------------------------------------------------------------------
__global__ void norm_k(const float* __restrict__ f1, const float* __restrict__ f2,
                       u16* __restrict__ nfh, u16* __restrict__ nfl) {
    const int w = threadIdx.x >> 6, lane = threadIdx.x & 63;
    const int row = blockIdx.x * 4 + w;
    const float* src = (row < NB1) ? (f1 + (size_t)row * NFD)
                                   : (f2 + (size_t)(row - NB1) * NFD);
    const float2 v = *reinterpret_cast<const float2*>(src + 2 * lane);
    float s = v.x * v.x + v.y * v.y;
#pragma unroll
    for (int m = 32; m >= 1; m >>= 1) s += __shfl_xor(s, m, 64);
    const float inv = 1.0f / fmaxf(sqrtf(s), 1e-12f);
    const float x0 = v.x * inv, x1 = v.y * inv;
    const u16 h0 = f2bf(x0), h1 = f2bf(x1);
    const u16 l0 = f2bf(x0 - bf2f(h0)), l1 = f2bf(x1 - bf2f(h1));
    ((unsigned*)(nfh + (size_t)row * NFD))[lane] = (unsigned)h0 | ((unsigned)h1 << 16);
    ((unsigned*)(nfl + (size_t)row * NFD))[lane] = (unsigned)l0 | ((unsigned)l1 << 16);
}

// ---------------------------------------------------------------------------
// B-tile stage via global_load_lds, pre-swizzled source (linear LDS dest).
// Storage: LDS byte (row*256 + slot*16) holds global k-chunk (slot ^ (row&15)).
// ---------------------------------------------------------------------------
__device__ __forceinline__ void stage_tile(const u16* __restrict__ nfh,
                                           const u16* __restrict__ nfl,
                                           int col0, char* bufH, char* bufL,
                                           int w, int lane) {
#pragma unroll
    for (int i = 0; i < 4; ++i) {
        const int base = w * 4096 + i * 1024;
        const int d    = base + lane * 16;
        const int sr   = d >> 8;            // dest row 0..127
        const int slot = (d >> 4) & 15;
        const int kc   = slot ^ (sr & 15);  // source k-chunk (involution)
        const u16* gh = nfh + (size_t)(col0 + sr) * NFD + kc * 8;
        const u16* gl = nfl + (size_t)(col0 + sr) * NFD + kc * 8;
        gl16(gh, bufH + base);
        gl16(gl, bufL + base);
    }
}

// ---------------------------------------------------------------------------
// Kernel 2: MFMA sim-stats. Grid (4 quarters, 64 row-tiles), 512 thr = 8 waves
// (4 row-stripes x 2 col-stripes; fa=2, fb=4). A-frags in registers (loaded
// once, tile-invariant). LDS = B double-buffer 2x64KB, 4-bit XOR swizzle.
// sim = Ah*Bh + Ah*Bl + Al*Bh (lo*lo dropped, ~2^-18).
// ---------------------------------------------------------------------------
__global__ __launch_bounds__(512, 1) void simstat_mfma(const u16* __restrict__ nfh,
                                                       const u16* __restrict__ nfl,
                                                       float* __restrict__ posp,
                                                       float* __restrict__ sexpp) {
    extern __shared__ __align__(16) char smem[];   // 131072 = 2 x (BH 32K + BL 32K)

    const int q    = blockIdx.x;
    const int rt   = blockIdx.y;
    const int row0 = rt * BROWS;
    const int col0q = q * QCOLS;
    const bool same = ((row0 >= NB1) == (q >= 2));
    const int p = q & 1;

    const int t    = threadIdx.x;
    const int w    = t >> 6;
    const int lane = t & 63;
    const int lr   = lane & 15;
    const int lg   = lane >> 4;
    const int rowbase = 32 * (w & 3);
    const int colbase = 64 * (w >> 1 >> 1);  // 64*(w>>2)

    // stage B tile 0 into buf0 (async)
    stage_tile(nfh, nfl, col0q, smem, smem + 32768, w, lane);

    // A fragments -> registers: rows row0+rowbase..+31, full K, hi+lo
    bf16x8 ah[4][2], al[4][2];
#pragma unroll
    for (int ks = 0; ks < 4; ++ks)
#pragma unroll
        for (int fa = 0; fa < 2; ++fa) {
            const size_t off = (size_t)(row0 + rowbase + 16 * fa + lr) * NFD + 32 * ks + 8 * lg;
            ah[ks][fa] = *reinterpret_cast<const bf16x8*>(nfh + off);
            al[ks][fa] = *reinterpret_cast<const bf16x8*>(nfl + off);
        }

    __syncthreads();   // drains vmcnt: tile0 + A loads complete

    float stat[2][4];
#pragma unroll
    for (int fa = 0; fa < 2; ++fa)
#pragma unroll
        for (int r = 0; r < 4; ++r) stat[fa][r] = same ? -3.0e38f : 0.0f;
    const float invtau = 1.0f / 0.07f;

#pragma unroll 1
    for (int tile = 0; tile < NTILES; ++tile) {
        char* bufH = smem + (tile & 1) * 65536;
        char* bufL = bufH + 32768;
        if (tile + 1 < NTILES) {
            char* nbuf = smem + ((tile + 1) & 1) * 65536;
            stage_tile(nfh, nfl, col0q + (tile + 1) * BCOLS, nbuf, nbuf + 32768, w, lane);
        }

        f32x4 acc[2][4];
#pragma unroll
        for (int fa = 0; fa < 2; ++fa)
#pragma unroll
            for (int fb = 0; fb < 4; ++fb) {
                f32x4 z = {0.0f, 0.0f, 0.0f, 0.0f};
                acc[fa][fb] = z;
            }

#pragma unroll
        for (int ks = 0; ks < 4; ++ks) {
            bf16x8 bh[4], bl[4];
#pragma unroll
            for (int fb = 0; fb < 4; ++fb) {
                const int row = colbase + 16 * fb + lr;        // row&15 == lr
                const int off = row * 256 + ((((ks << 2) + lg) ^ lr) << 4);
                bh[fb] = *reinterpret_cast<const bf16x8*>(bufH + off);
                bl[fb] = *reinterpret_cast<const bf16x8*>(bufL + off);
            }
#pragma unroll
            for (int fa = 0; fa < 2; ++fa)
#pragma unroll
                for (int fb = 0; fb < 4; ++fb) {
                    acc[fa][fb] = __builtin_amdgcn_mfma_f32_16x16x32_bf16(ah[ks][fa], bh[fb], acc[fa][fb], 0, 0, 0);
                    acc[fa][fb] = __builtin_amdgcn_mfma_f32_16x16x32_bf16(ah[ks][fa], bl[fb], acc[fa][fb], 0, 0, 0);
                    acc[fa][fb] = __builtin_amdgcn_mfma_f32_16x16x32_bf16(al[ks][fa], bh[fb], acc[fa][fb], 0, 0, 0);
                }
        }

        // fold acc into stat; C/D: col=lane&15, row=4*lg+reg (m89-verified)
        const int col0 = col0q + tile * BCOLS;
        if (same) {
#pragma unroll
            for (int fa = 0; fa < 2; ++fa)
#pragma unroll
                for (int fb = 0; fb < 4; ++fb)
#pragma unroll
                    for (int r = 0; r < 4; ++r) {
                        const int grow = row0 + rowbase + 16 * fa + 4 * lg + r;
                        const int gcol = col0 + colbase + 16 * fb + lr;
                        const float sim = acc[fa][fb][r] * invtau;
                        stat[fa][r] = (grow == gcol) ? stat[fa][r] : fmaxf(stat[fa][r], sim);
                    }
        } else {
#pragma unroll
            for (int fa = 0; fa < 2; ++fa)
#pragma unroll
                for (int fb = 0; fb < 4; ++fb)
#pragma unroll
                    for (int r = 0; r < 4; ++r)
                        stat[fa][r] += __expf(acc[fa][fb][r] * invtau);
        }

        __syncthreads();   // next buf ready; all waves done with current buf
    }

    // reduce over the 16 columns held across lr (lane bits 0..3)
#pragma unroll
    for (int m = 1; m <= 8; m <<= 1) {
#pragma unroll
        for (int fa = 0; fa < 2; ++fa)
#pragma unroll
            for (int r = 0; r < 4; ++r) {
                const float o = __shfl_xor(stat[fa][r], m, 64);
                stat[fa][r] = same ? fmaxf(stat[fa][r], o) : (stat[fa][r] + o);
            }
    }

    // cross-wave combine: scratch[colwave][128 rows]
    float* scratch = (float*)smem;
    if (lr == 0) {
#pragma unroll
        for (int fa = 0; fa < 2; ++fa)
#pragma unroll
            for (int r = 0; r < 4; ++r) {
                const int rl = rowbase + 16 * fa + 4 * lg + r;
                scratch[(w >> 2) * 128 + rl] = stat[fa][r];
            }
    }
    __syncthreads();
    if (t < 128) {
        const float v0 = scratch[t];
        const float v1 = scratch[128 + t];
        const float v = same ? fmaxf(v0, v1) : (v0 + v1);
        (same ? posp : sexpp)[(size_t)p * NBTOT + row0 + t] = v;
    }
}

// ---------------------------------------------------------------------------
// Kernel 3: combine quarter-partials, per-row loss, mean. One block.
// loss_i = log(exp(pos)+S) - pos = log1p(S * exp(-pos))
// ---------------------------------------------------------------------------
__global__ void loss_k(const float* __restrict__ posp, const float* __restrict__ sexpp,
                       float* __restrict__ out) {
    const int t = threadIdx.x;  // 256
    float s = 0.0f;
    for (int i = t; i < NBTOT; i += 256) {
        const float pv = fmaxf(posp[i], posp[NBTOT + i]);
        const float se = sexpp[i] + sexpp[NBTOT + i];
        s += log1pf(se * __expf(-pv));
    }
#pragma unroll
    for (int m = 32; m >= 1; m >>= 1) s += __shfl_xor(s, m, 64);
    __shared__ float part[4];
    if ((t & 63) == 0) part[t >> 6] = s;
    __syncthreads();
    if (t == 0) out[0] = (part[0] + part[1] + part[2] + part[3]) / (float)NBTOT;
}

// ---------------------------------------------------------------------------
extern "C" void kernel_launch(void* const* d_in, const int* in_sizes, int n_in,
                              void* d_out, int out_size, void* d_ws, size_t ws_size,
                              hipStream_t stream) {
    const float* f1 = (const float*)d_in[0];
    const float* f2 = (const float*)d_in[1];

    u16*   nfh   = (u16*)d_ws;                       // 8192*128 bf16 = 2 MB
    u16*   nfl   = nfh + (size_t)NBTOT * NFD;        // 2 MB
    float* posp  = (float*)(nfl + (size_t)NBTOT * NFD);
    float* sexpp = posp + 2 * NBTOT;

    (void)hipFuncSetAttribute(reinterpret_cast<const void*>(simstat_mfma),
                              hipFuncAttributeMaxDynamicSharedMemorySize, 131072);

    norm_k<<<NBTOT / 4, 256, 0, stream>>>(f1, f2, nfh, nfl);
    simstat_mfma<<<dim3(4, 64), 512, 131072, stream>>>(nfh, nfl, posp, sexpp);
    loss_k<<<1, 256, 0, stream>>>(posp, sexpp, (float*)d_out);
}